// Round 7
// baseline (137.763 us; speedup 1.0000x reference)
//
#include <hip/hip_runtime.h>

#define HH 512
#define WW 512
#define RSTRIP 64          // output rows per block-strip (512 ncc blocks)
#define DR 16              // ring depth (rows)
#define PW 520             // padded row: [4 zeros][512 data][4 zeros]

#define WAITVM(n) asm volatile("s_waitcnt vmcnt(" #n ")" ::: "memory")

// Async global->LDS, 16B/lane. LDS dest = wave-uniform base + lane*16.
__device__ __forceinline__ void gload16(const float* g, float* l) {
    __builtin_amdgcn_global_load_lds(
        (const __attribute__((address_space(1))) void*)g,
        (__attribute__((address_space(3))) void*)l, 16, 0, 0);
}

// Read the 10-float window (cols 2t-4 .. 2t+5) of one padded ring row.
// Data starts at float 4, so window = floats 2t .. 2t+9: five aligned float2s.
__device__ __forceinline__ void rdwin(const float* __restrict__ rowp, int t,
                                      float (&w)[10]) {
    const float2* p = reinterpret_cast<const float2*>(rowp) + t;
#pragma unroll
    for (int i = 0; i < 5; ++i) {
        float2 x = p[i];
        w[2 * i] = x.x;
        w[2 * i + 1] = x.y;
    }
}

// 9-wide sliding fold of d[0..9] into b[0..1] (2 output cols).
__device__ __forceinline__ void fold2(const float d[10], float* b) {
    float s = (((d[0] + d[1]) + (d[2] + d[3])) +
               ((d[4] + d[5]) + (d[6] + d[7]))) + d[8];
    b[0] += s;
    s += d[9] - d[0];
    b[1] += s;
}

__device__ __forceinline__ void acc_lead2(const float (&wi)[10],
                                          const float (&wj)[10],
                                          float (&B)[5][2]) {
    float d[10];
    fold2(wi, B[0]);
    fold2(wj, B[1]);
#pragma unroll
    for (int i = 0; i < 10; ++i) d[i] = wi[i] * wi[i];
    fold2(d, B[2]);
#pragma unroll
    for (int i = 0; i < 10; ++i) d[i] = wj[i] * wj[i];
    fold2(d, B[3]);
#pragma unroll
    for (int i = 0; i < 10; ++i) d[i] = wi[i] * wj[i];
    fold2(d, B[4]);
}

__device__ __forceinline__ void upd2_full(const float (&li)[10], const float (&lj)[10],
                                          const float (&ti)[10], const float (&tj)[10],
                                          float (&B)[5][2]) {
    float d[10];
#pragma unroll
    for (int i = 0; i < 10; ++i) d[i] = li[i] - ti[i];
    fold2(d, B[0]);
#pragma unroll
    for (int i = 0; i < 10; ++i) d[i] = lj[i] - tj[i];
    fold2(d, B[1]);
#pragma unroll
    for (int i = 0; i < 10; ++i) d[i] = fmaf(li[i], li[i], -(ti[i] * ti[i]));
    fold2(d, B[2]);
#pragma unroll
    for (int i = 0; i < 10; ++i) d[i] = fmaf(lj[i], lj[i], -(tj[i] * tj[i]));
    fold2(d, B[3]);
#pragma unroll
    for (int i = 0; i < 10; ++i) d[i] = fmaf(li[i], lj[i], -(ti[i] * tj[i]));
    fold2(d, B[4]);
}

__device__ __forceinline__ void upd2_trail(const float (&ti)[10], const float (&tj)[10],
                                           float (&B)[5][2]) {
    float d[10];
#pragma unroll
    for (int i = 0; i < 10; ++i) d[i] = -ti[i];
    fold2(d, B[0]);
#pragma unroll
    for (int i = 0; i < 10; ++i) d[i] = -tj[i];
    fold2(d, B[1]);
#pragma unroll
    for (int i = 0; i < 10; ++i) d[i] = -(ti[i] * ti[i]);
    fold2(d, B[2]);
#pragma unroll
    for (int i = 0; i < 10; ++i) d[i] = -(tj[i] * tj[i]);
    fold2(d, B[3]);
#pragma unroll
    for (int i = 0; i < 10; ++i) d[i] = -(ti[i] * tj[i]);
    fold2(d, B[4]);
}

__device__ __forceinline__ float cc2(const float (&B)[5][2]) {
    const float inv81 = 1.f / 81.f;
    float a = 0.f;
#pragma unroll
    for (int o = 0; o < 2; ++o) {
        float IS = B[0][o], JS = B[1][o];
        float I2 = B[2][o], J2 = B[3][o], IJ = B[4][o];
        float cross = fmaf(-(IS * JS), inv81, IJ);
        float Iv = fmaf(-(IS * IS), inv81, I2);
        float Jv = fmaf(-(JS * JS), inv81, J2);
        float denom = fmaf(Iv, Jv, 1e-5f);
        a = fmaf(cross * cross, __builtin_amdgcn_rcpf(denom), a);
    }
    return a;
}

// 256 threads (4 waves) per block; block owns a 64-row x 512-col strip.
// Shared padded ring of 16 rows x {I,J}. Fill distance 11, vmcnt(4).
// Each lane owns 2 output cols; window reads are aligned float2s (no edge code).
__global__ __launch_bounds__(256) void ncc_kernel(const float* __restrict__ I,
                                                  const float* __restrict__ J,
                                                  float* __restrict__ ws) {
    __shared__ float ring[2][DR][PW];           // 66560 B
    const int T = threadIdx.x;                  // owns cols 2T, 2T+1
    const int wv = T >> 6;                      // wave 0..3
    const int lane = T & 63;
    const int b = blockIdx.x >> 3;
    const int r0 = (blockIdx.x & 7) << 6;

    const float* Ib = I + (size_t)b * (HH * WW);
    const float* Jb = J + (size_t)b * (HH * WW);
    const int img = wv >> 1;                    // waves 0,1 fill I; 2,3 fill J
    const int half = wv & 1;                    // which 256-float half of the row
    const float* src_base = img ? Jb : Ib;

    // zero the side pads of every slot: 2 imgs x 16 slots x 8 pad floats = 256
    {
        const int pimg = T >> 7;
        const int psl = (T >> 3) & 15;
        const int k = T & 7;
        ring[pimg][psl][(k < 4) ? k : (512 + k)] = 0.f;
    }
    // strip 0: zero data region of slots for rows -4..-1 (slots 12..15)
    if (r0 == 0) {
#pragma unroll
        for (int q = 0; q < 4; ++q) {
            const int id = q * 256 + T;          // 0..1023
            const int zimg = id >> 9;
            const int rem = id & 511;
            const int zsl = 12 + (rem >> 7);
            reinterpret_cast<float4*>(&ring[zimg][zsl][4])[rem & 127] =
                make_float4(0.f, 0.f, 0.f, 0.f);
        }
    }
    // prologue fills: rows r0-4 .. r0+10 (all <= 458, no clamp needed)
    for (int rr = r0 - 4; rr <= r0 + 10; ++rr) {
        if (rr >= 0) {
            gload16(src_base + (size_t)rr * WW + (half << 8) + (lane << 2),
                    &ring[img][rr & 15][4 + (half << 8)]);
        }
    }
    asm volatile("s_waitcnt vmcnt(0)" ::: "memory");
    __syncthreads();

    float B[5][2];
#pragma unroll
    for (int k = 0; k < 5; ++k) { B[k][0] = 0.f; B[k][1] = 0.f; }

    // warm-up: fold rows r0-4 .. r0+4 (negative rows hit zeroed slots)
    for (int j = r0 - 4; j <= r0 + 4; ++j) {
        float wi[10], wj[10];
        rdwin(&ring[0][j & 15][0], T, wi);
        rdwin(&ring[1][j & 15][0], T, wj);
        acc_lead2(wi, wj, B);
    }

    // ping-pong window registers, preloaded for step h=0
    float Ali[10], Alj[10], Ati[10], Atj[10];
    float Bli[10], Blj[10], Bti[10], Btj[10];
    rdwin(&ring[0][(r0 + 5) & 15][0], T, Ali);
    rdwin(&ring[1][(r0 + 5) & 15][0], T, Alj);
    rdwin(&ring[0][(r0 - 4) & 15][0], T, Ati);
    rdwin(&ring[1][(r0 - 4) & 15][0], T, Atj);

    float acc = 0.f;

#define STEP(h, CLi, CLj, CTi, CTj, NLi, NLj, NTi, NTj)                       \
    {                                                                         \
        WAITVM(4);                                                            \
        __builtin_amdgcn_s_barrier();                                         \
        {   /* fill row h+11 -> slot (h-5): dead since step h-1 (barriered) */\
            const int rr = r0 + (h) + 11;                                     \
            const int rc = rr > HH - 1 ? HH - 1 : rr;                         \
            gload16(src_base + (size_t)rc * WW + (half << 8) + (lane << 2),   \
                    &ring[img][rr & 15][4 + (half << 8)]);                    \
        }                                                                     \
        acc += cc2(B);                                                        \
        if ((h) < RSTRIP - 1) {                                               \
            if (r0 + (h) + 5 < HH) upd2_full(CLi, CLj, CTi, CTj, B);          \
            else                   upd2_trail(CTi, CTj, B);                   \
            const int jl = r0 + (h) + 6, jt = r0 + (h) - 3;                   \
            rdwin(&ring[0][jl & 15][0], T, NLi);                              \
            rdwin(&ring[1][jl & 15][0], T, NLj);                              \
            rdwin(&ring[0][jt & 15][0], T, NTi);                              \
            rdwin(&ring[1][jt & 15][0], T, NTj);                              \
        }                                                                     \
    }

    for (int k = 0; k < RSTRIP / 2; ++k) {
        const int h0 = 2 * k, h1 = 2 * k + 1;
        STEP(h0, Ali, Alj, Ati, Atj, Bli, Blj, Bti, Btj);
        STEP(h1, Bli, Blj, Bti, Btj, Ali, Alj, Ati, Atj);
    }
#undef STEP

    // block reduction (drain async fills before reusing ring LDS)
#pragma unroll
    for (int off = 32; off; off >>= 1) acc += __shfl_down(acc, off);
    __syncthreads();
    if (lane == 0) ring[0][0][wv] = acc;
    __syncthreads();
    if (T == 0)
        atomicAdd(&ws[0], (ring[0][0][0] + ring[0][0][1]) +
                          (ring[0][0][2] + ring[0][0][3]));
}

__global__ __launch_bounds__(256) void reg_kernel(const float* __restrict__ P,
                                                  float* __restrict__ ws) {
    __shared__ float sh[8];
    const int T = threadIdx.x;
    const int c4 = T & 127;                         // 128 float4s = one row
    const int strip = (blockIdx.x << 1) | (T >> 7); // 0..4095 over 65536 rows
    const size_t row0 = (size_t)strip << 4;         // *16 rows per strip
    const bool slast = ((strip & 31) == 31);        // ends at image row 511
    const float* rp = P + row0 * WW + (c4 << 2);

    float sdx = 0.f, sdy = 0.f;
    float4 cur = *reinterpret_cast<const float4*>(rp);
#pragma unroll 8
    for (int i = 0; i < 16; ++i) {
        float d0 = cur.y - cur.x, d1 = cur.z - cur.y, d2 = cur.w - cur.z;
        sdx += d0 * d0 + d1 * d1 + d2 * d2;
        if (c4 < 127) {                             // neighbor elem (cache hit)
            float nx = rp[(size_t)i * WW + 4];
            float d3 = nx - cur.w;
            sdx += d3 * d3;
        }
        if (i < 15) {
            float4 nr = *reinterpret_cast<const float4*>(rp + (size_t)(i + 1) * WW);
            float e0 = nr.x - cur.x, e1 = nr.y - cur.y;
            float e2 = nr.z - cur.z, e3 = nr.w - cur.w;
            sdy += e0 * e0 + e1 * e1 + e2 * e2 + e3 * e3;
            cur = nr;
        } else if (!slast) {
            float4 nr = *reinterpret_cast<const float4*>(rp + (size_t)16 * WW);
            float e0 = nr.x - cur.x, e1 = nr.y - cur.y;
            float e2 = nr.z - cur.z, e3 = nr.w - cur.w;
            sdy += e0 * e0 + e1 * e1 + e2 * e2 + e3 * e3;
        }
    }

#pragma unroll
    for (int off = 32; off; off >>= 1) {
        sdx += __shfl_down(sdx, off);
        sdy += __shfl_down(sdy, off);
    }
    if ((T & 63) == 0) { sh[T >> 6] = sdx; sh[4 + (T >> 6)] = sdy; }
    __syncthreads();
    if (T == 0) {
        atomicAdd(&ws[1], sh[0] + sh[1] + sh[2] + sh[3]);
        atomicAdd(&ws[2], sh[4] + sh[5] + sh[6] + sh[7]);
    }
}

__global__ void finalize_kernel(const float* __restrict__ ws,
                                float* __restrict__ out) {
    float cc_sum = ws[0], dx_sum = ws[1], dy_sum = ws[2];
    float loss_sim = -(cc_sum / 16777216.f);   // 64*512*512
    float mdx = dx_sum / 33488896.f;           // 64*2*512*511
    float mdy = dy_sum / 33488896.f;           // 64*2*511*512
    float loss_reg = (mdx + mdy) * 0.5f * 0.1f;
    out[0] = loss_sim;
    out[1] = loss_reg;
    out[2] = loss_sim + loss_reg;
}

extern "C" void kernel_launch(void* const* d_in, const int* in_sizes, int n_in,
                              void* d_out, int out_size, void* d_ws, size_t ws_size,
                              hipStream_t stream) {
    const float* I = (const float*)d_in[0];   // target_proj
    const float* J = (const float*)d_in[1];   // warped_moving
    const float* P = (const float*)d_in[2];   // phi
    float* out = (float*)d_out;
    float* ws = (float*)d_ws;

    hipMemsetAsync(d_ws, 0, 3 * sizeof(float), stream);
    ncc_kernel<<<512, 256, 0, stream>>>(I, J, ws);   // 2 blocks/CU (66.5 KB LDS)
    reg_kernel<<<2048, 256, 0, stream>>>(P, ws);     // streaming, 8 blocks/CU
    finalize_kernel<<<1, 1, 0, stream>>>(ws, out);
}

// Round 8
// 113.156 us; speedup vs baseline: 1.2175x; 1.2175x over previous
//
#include <hip/hip_runtime.h>

#define HH 512
#define WW 512
#define RSTRIP 64          // ncc: output rows per block-strip (512 blocks)
#define DR 16              // ring depth (rows)
#define PW 520             // padded row: [4 zeros][512 data][4 zeros]

#define WAITVM(n) asm volatile("s_waitcnt vmcnt(" #n ")" ::: "memory")

// Async global->LDS, 16B/lane. LDS dest = wave-uniform base + lane*16.
__device__ __forceinline__ void gload16(const float* g, float* l) {
    __builtin_amdgcn_global_load_lds(
        (const __attribute__((address_space(1))) void*)g,
        (__attribute__((address_space(3))) void*)l, 16, 0, 0);
}

// Read the 10-float window (cols 2t-4 .. 2t+5) of one padded ring row.
// Data starts at float 4, so window = floats 2t .. 2t+9: five aligned float2s.
__device__ __forceinline__ void rdwin(const float* __restrict__ rowp, int t,
                                      float (&w)[10]) {
    const float2* p = reinterpret_cast<const float2*>(rowp) + t;
#pragma unroll
    for (int i = 0; i < 5; ++i) {
        float2 x = p[i];
        w[2 * i] = x.x;
        w[2 * i + 1] = x.y;
    }
}

// 9-wide sliding fold of d[0..9] into b[0..1] (2 output cols).
__device__ __forceinline__ void fold2(const float d[10], float* b) {
    float s = (((d[0] + d[1]) + (d[2] + d[3])) +
               ((d[4] + d[5]) + (d[6] + d[7]))) + d[8];
    b[0] += s;
    s += d[9] - d[0];
    b[1] += s;
}

__device__ __forceinline__ void acc_lead2(const float (&wi)[10],
                                          const float (&wj)[10],
                                          float (&B)[5][2]) {
    float d[10];
    fold2(wi, B[0]);
    fold2(wj, B[1]);
#pragma unroll
    for (int i = 0; i < 10; ++i) d[i] = wi[i] * wi[i];
    fold2(d, B[2]);
#pragma unroll
    for (int i = 0; i < 10; ++i) d[i] = wj[i] * wj[i];
    fold2(d, B[3]);
#pragma unroll
    for (int i = 0; i < 10; ++i) d[i] = wi[i] * wj[i];
    fold2(d, B[4]);
}

__device__ __forceinline__ void upd2_full(const float (&li)[10], const float (&lj)[10],
                                          const float (&ti)[10], const float (&tj)[10],
                                          float (&B)[5][2]) {
    float d[10];
#pragma unroll
    for (int i = 0; i < 10; ++i) d[i] = li[i] - ti[i];
    fold2(d, B[0]);
#pragma unroll
    for (int i = 0; i < 10; ++i) d[i] = lj[i] - tj[i];
    fold2(d, B[1]);
#pragma unroll
    for (int i = 0; i < 10; ++i) d[i] = fmaf(li[i], li[i], -(ti[i] * ti[i]));
    fold2(d, B[2]);
#pragma unroll
    for (int i = 0; i < 10; ++i) d[i] = fmaf(lj[i], lj[i], -(tj[i] * tj[i]));
    fold2(d, B[3]);
#pragma unroll
    for (int i = 0; i < 10; ++i) d[i] = fmaf(li[i], lj[i], -(ti[i] * tj[i]));
    fold2(d, B[4]);
}

__device__ __forceinline__ void upd2_trail(const float (&ti)[10], const float (&tj)[10],
                                           float (&B)[5][2]) {
    float d[10];
#pragma unroll
    for (int i = 0; i < 10; ++i) d[i] = -ti[i];
    fold2(d, B[0]);
#pragma unroll
    for (int i = 0; i < 10; ++i) d[i] = -tj[i];
    fold2(d, B[1]);
#pragma unroll
    for (int i = 0; i < 10; ++i) d[i] = -(ti[i] * ti[i]);
    fold2(d, B[2]);
#pragma unroll
    for (int i = 0; i < 10; ++i) d[i] = -(tj[i] * tj[i]);
    fold2(d, B[3]);
#pragma unroll
    for (int i = 0; i < 10; ++i) d[i] = -(ti[i] * tj[i]);
    fold2(d, B[4]);
}

__device__ __forceinline__ float cc2(const float (&B)[5][2]) {
    const float inv81 = 1.f / 81.f;
    float a = 0.f;
#pragma unroll
    for (int o = 0; o < 2; ++o) {
        float IS = B[0][o], JS = B[1][o];
        float I2 = B[2][o], J2 = B[3][o], IJ = B[4][o];
        float cross = fmaf(-(IS * JS), inv81, IJ);
        float Iv = fmaf(-(IS * IS), inv81, I2);
        float Jv = fmaf(-(JS * JS), inv81, J2);
        float denom = fmaf(Iv, Jv, 1e-5f);
        a = fmaf(cross * cross, __builtin_amdgcn_rcpf(denom), a);
    }
    return a;
}

// 256 threads (4 waves) per block; block owns a 64-row x 512-col strip.
// Shared padded ring of 16 rows x {I,J}. Fill distance 11, per-wave vmcnt(4):
// after WAITVM+barrier, every wave's fills through row h+7 are complete.
__global__ __launch_bounds__(256) void ncc_kernel(const float* __restrict__ I,
                                                  const float* __restrict__ J,
                                                  float* __restrict__ ws) {
    __shared__ float ring[2][DR][PW];           // 66560 B -> 2 blocks/CU
    const int T = threadIdx.x;                  // owns cols 2T, 2T+1
    const int wv = T >> 6;                      // wave 0..3
    const int lane = T & 63;
    const int b = blockIdx.x >> 3;
    const int r0 = (blockIdx.x & 7) << 6;

    const float* Ib = I + (size_t)b * (HH * WW);
    const float* Jb = J + (size_t)b * (HH * WW);
    const int img = wv >> 1;                    // waves 0,1 fill I; 2,3 fill J
    const int half = wv & 1;                    // which 256-float half of the row
    const float* src_base = img ? Jb : Ib;

    // zero the side pads of every slot: 2 imgs x 16 slots x 8 pad floats = 256
    {
        const int pimg = T >> 7;
        const int psl = (T >> 3) & 15;
        const int k = T & 7;
        ring[pimg][psl][(k < 4) ? k : (512 + k)] = 0.f;
    }
    // strip 0: zero data region of slots for rows -4..-1 (slots 12..15)
    if (r0 == 0) {
#pragma unroll
        for (int q = 0; q < 4; ++q) {
            const int id = q * 256 + T;          // 0..1023
            const int zimg = id >> 9;
            const int rem = id & 511;
            const int zsl = 12 + (rem >> 7);
            reinterpret_cast<float4*>(&ring[zimg][zsl][4])[rem & 127] =
                make_float4(0.f, 0.f, 0.f, 0.f);
        }
    }
    // prologue fills: rows r0-4 .. r0+10 (all <= 458, no clamp needed)
    for (int rr = r0 - 4; rr <= r0 + 10; ++rr) {
        if (rr >= 0) {
            gload16(src_base + (size_t)rr * WW + (half << 8) + (lane << 2),
                    &ring[img][rr & 15][4 + (half << 8)]);
        }
    }
    asm volatile("s_waitcnt vmcnt(0)" ::: "memory");
    __syncthreads();

    float B[5][2];
#pragma unroll
    for (int k = 0; k < 5; ++k) { B[k][0] = 0.f; B[k][1] = 0.f; }

    // warm-up: fold rows r0-4 .. r0+4 (negative rows hit zeroed slots)
    for (int j = r0 - 4; j <= r0 + 4; ++j) {
        float wi[10], wj[10];
        rdwin(&ring[0][j & 15][0], T, wi);
        rdwin(&ring[1][j & 15][0], T, wj);
        acc_lead2(wi, wj, B);
    }

    // ping-pong window registers, preloaded for step h=0
    float Ali[10], Alj[10], Ati[10], Atj[10];
    float Bli[10], Blj[10], Bti[10], Btj[10];
    rdwin(&ring[0][(r0 + 5) & 15][0], T, Ali);
    rdwin(&ring[1][(r0 + 5) & 15][0], T, Alj);
    rdwin(&ring[0][(r0 - 4) & 15][0], T, Ati);
    rdwin(&ring[1][(r0 - 4) & 15][0], T, Atj);

    float acc = 0.f;

#define STEP(h, CLi, CLj, CTi, CTj, NLi, NLj, NTi, NTj)                       \
    {                                                                         \
        WAITVM(4);                                                            \
        __builtin_amdgcn_s_barrier();                                         \
        {   /* fill row h+11 -> slot (h-5): dead since step h-1 (barriered) */\
            const int rr = r0 + (h) + 11;                                     \
            const int rc = rr > HH - 1 ? HH - 1 : rr;                         \
            gload16(src_base + (size_t)rc * WW + (half << 8) + (lane << 2),   \
                    &ring[img][rr & 15][4 + (half << 8)]);                    \
        }                                                                     \
        acc += cc2(B);                                                        \
        if ((h) < RSTRIP - 1) {                                               \
            if (r0 + (h) + 5 < HH) upd2_full(CLi, CLj, CTi, CTj, B);          \
            else                   upd2_trail(CTi, CTj, B);                   \
            const int jl = r0 + (h) + 6, jt = r0 + (h) - 3;                   \
            rdwin(&ring[0][jl & 15][0], T, NLi);                              \
            rdwin(&ring[1][jl & 15][0], T, NLj);                              \
            rdwin(&ring[0][jt & 15][0], T, NTi);                              \
            rdwin(&ring[1][jt & 15][0], T, NTj);                              \
        }                                                                     \
    }

    for (int k = 0; k < RSTRIP / 2; ++k) {
        const int h0 = 2 * k, h1 = 2 * k + 1;
        STEP(h0, Ali, Alj, Ati, Atj, Bli, Blj, Bti, Btj);
        STEP(h1, Bli, Blj, Bti, Btj, Ali, Alj, Ati, Atj);
    }
#undef STEP

    // block reduction (syncthreads drains pending async fills before LDS reuse)
#pragma unroll
    for (int off = 32; off; off >>= 1) acc += __shfl_down(acc, off);
    __syncthreads();
    if (lane == 0) ring[0][0][wv] = acc;
    __syncthreads();
    if (T == 0)
        atomicAdd(&ws[0], (ring[0][0][0] + ring[0][0][1]) +
                          (ring[0][0][2] + ring[0][0][3]));
}

// reg: EXACT R6 configuration (measured ~21 us): 1024 blocks, 32-row
// register-carried strips, 2 strips per 256-thread block.
__global__ __launch_bounds__(256) void reg_kernel(const float* __restrict__ P,
                                                  float* __restrict__ ws) {
    __shared__ float sh[8];
    const int T = threadIdx.x;
    const int c4 = T & 127;                         // 128 float4s = one row
    const int strip = (blockIdx.x << 1) | (T >> 7); // 0..2047 over 65536 rows
    const size_t row0 = (size_t)strip << 5;         // *32 rows per strip
    const bool slast = ((strip & 15) == 15);        // ends at image row 511
    const float* rp = P + row0 * WW + (c4 << 2);

    float sdx = 0.f, sdy = 0.f;
    float4 cur = *reinterpret_cast<const float4*>(rp);
#pragma unroll 8
    for (int i = 0; i < 32; ++i) {
        float d0 = cur.y - cur.x, d1 = cur.z - cur.y, d2 = cur.w - cur.z;
        sdx += d0 * d0 + d1 * d1 + d2 * d2;
        if (c4 < 127) {                             // neighbor elem (cache hit)
            float nx = rp[(size_t)i * WW + 4];
            float d3 = nx - cur.w;
            sdx += d3 * d3;
        }
        if (i < 31) {
            float4 nr = *reinterpret_cast<const float4*>(rp + (size_t)(i + 1) * WW);
            float e0 = nr.x - cur.x, e1 = nr.y - cur.y;
            float e2 = nr.z - cur.z, e3 = nr.w - cur.w;
            sdy += e0 * e0 + e1 * e1 + e2 * e2 + e3 * e3;
            cur = nr;
        } else if (!slast) {
            float4 nr = *reinterpret_cast<const float4*>(rp + (size_t)32 * WW);
            float e0 = nr.x - cur.x, e1 = nr.y - cur.y;
            float e2 = nr.z - cur.z, e3 = nr.w - cur.w;
            sdy += e0 * e0 + e1 * e1 + e2 * e2 + e3 * e3;
        }
    }

#pragma unroll
    for (int off = 32; off; off >>= 1) {
        sdx += __shfl_down(sdx, off);
        sdy += __shfl_down(sdy, off);
    }
    if ((T & 63) == 0) { sh[T >> 6] = sdx; sh[4 + (T >> 6)] = sdy; }
    __syncthreads();
    if (T == 0) {
        atomicAdd(&ws[1], sh[0] + sh[1] + sh[2] + sh[3]);
        atomicAdd(&ws[2], sh[4] + sh[5] + sh[6] + sh[7]);
    }
}

__global__ void finalize_kernel(const float* __restrict__ ws,
                                float* __restrict__ out) {
    float cc_sum = ws[0], dx_sum = ws[1], dy_sum = ws[2];
    float loss_sim = -(cc_sum / 16777216.f);   // 64*512*512
    float mdx = dx_sum / 33488896.f;           // 64*2*512*511
    float mdy = dy_sum / 33488896.f;           // 64*2*511*512
    float loss_reg = (mdx + mdy) * 0.5f * 0.1f;
    out[0] = loss_sim;
    out[1] = loss_reg;
    out[2] = loss_sim + loss_reg;
}

extern "C" void kernel_launch(void* const* d_in, const int* in_sizes, int n_in,
                              void* d_out, int out_size, void* d_ws, size_t ws_size,
                              hipStream_t stream) {
    const float* I = (const float*)d_in[0];   // target_proj
    const float* J = (const float*)d_in[1];   // warped_moving
    const float* P = (const float*)d_in[2];   // phi
    float* out = (float*)d_out;
    float* ws = (float*)d_ws;

    hipMemsetAsync(d_ws, 0, 3 * sizeof(float), stream);
    ncc_kernel<<<512, 256, 0, stream>>>(I, J, ws);   // 2 blocks/CU (66.5 KB LDS)
    reg_kernel<<<1024, 256, 0, stream>>>(P, ws);     // R6 config, ~21 us
    finalize_kernel<<<1, 1, 0, stream>>>(ws, out);
}